// Round 2
// baseline (390.584 us; speedup 1.0000x reference)
//
#include <hip/hip_runtime.h>

typedef unsigned short u16;
typedef __attribute__((ext_vector_type(8))) short v8s;   // 8 bf16 = 4 VGPRs
typedef __attribute__((ext_vector_type(4))) float v4f;   // MFMA accumulator / float4
typedef __attribute__((ext_vector_type(4))) float f4;

#define HID 128
#define TM  64          // edges per tile
#define EFS 392         // EF LDS row stride (bf16 elements): 384 + 8 pad
#define FOS 132         // fp32 out-staging row stride: 128 + 4
#define PBLK 512        // persistent blocks: 2 per CU

__device__ __forceinline__ u16 f2b(float f) {            // fp32 -> bf16 RNE
    union { float f; unsigned u; } v; v.f = f;
    unsigned u = v.u;
    u += 0x7fffu + ((u >> 16) & 1u);
    return (u16)(u >> 16);
}

#define MFMA(A, B, C) __builtin_amdgcn_mfma_f32_16x16x32_bf16(A, B, C, 0, 0, 0)

// Workgroup barrier that drains ONLY LDS ops (lgkmcnt). Global loads stay in
// flight across it -- this is what keeps the gather prefetch pipelined.
// asm memory clobbers fence compiler reordering on both sides of s_barrier.
__device__ __forceinline__ void barw() {
    asm volatile("s_waitcnt lgkmcnt(0)" ::: "memory");
    __builtin_amdgcn_s_barrier();
    asm volatile("" ::: "memory");
}

// ---- weight fp32 -> bf16 pre-pass (once per launch, ~0.2 MB total) ----
// ws layout (u16 elems): Wp @0 (16384) | Wc @16384 | W1 @32768 (49152) | W2 @81920
__global__ void cvt_weights(const float* __restrict__ Wp, const float* __restrict__ Wc,
                            const float* __restrict__ W1, const float* __restrict__ W2,
                            u16* __restrict__ dst)
{
    int i = blockIdx.x * 256 + threadIdx.x;   // float4 index, 24576 total
    const float* s; int off;
    if (i < 4096)       { s = Wp; off = 0; }
    else if (i < 8192)  { s = Wc; off = 4096; }
    else if (i < 20480) { s = W1; off = 8192; }
    else                { s = W2; off = 20480; }
    int j = i - off;
    f4 v = ((const f4*)s)[j];
    u16* d = dst + (size_t)i * 4;
    d[0] = f2b(v[0]); d[1] = f2b(v[1]); d[2] = f2b(v[2]); d[3] = f2b(v[3]);
}

// Persistent pipelined kernel: 512 threads (8 waves, 2x4 wave tile of 64x128),
// grid-stride over edge tiles; next tile's gather is issued into registers
// before this tile's GEMM stages run.
__global__ __launch_bounds__(512, 4) void edge_attr_kernel(
    const float* __restrict__ x_src, const float* __restrict__ x_dst,
    const int* __restrict__ ei,
    const u16* __restrict__ wsW,                 // converted weights in d_ws
    const float* __restrict__ bp, const float* __restrict__ bc,
    const float* __restrict__ b1, const float* __restrict__ b2,
    float* __restrict__ out, int E, int ntiles)
{
    __shared__ __align__(16) u16 sEF[TM * EFS];  // 50176 B

    const u16* wsWp = wsW;
    const u16* wsWc = wsW + 16384;
    const u16* wsW1 = wsW + 32768;
    const u16* wsW2 = wsW + 81920;

    const int t  = threadIdx.x;
    const int* ei0 = ei;
    const int* ei1 = ei + E;

    // gather coords: this thread handles rows gr and gr+32, chunk gc
    const int gr = t >> 4;
    const int gc = (t & 15) << 3;

    const int lane = t & 63;
    const int ln = lane & 15;       // C-col / A-row within 16x16 tile
    const int lq = lane >> 4;       // quad: k-base lq*8; C-row base lq*4
    const int w  = t >> 6;          // wave 0..7
    const int r0 = (w >> 2) * 32;   // wave row base
    const int c0 = (w & 3) * 32;    // wave col base

    // ---- prefetch state (loop-carried registers) ----
    int iA0, iA1, iB0, iB1;                       // node ids for next tile
    f4 PA0, PA1, QA0, QA1, PB0, PB1, QB0, QB1;    // 8 x float4 = 32 VGPR

    auto pre_issue = [&](int tile) {              // edge-index loads (L2-ish)
        int e0 = tile * TM;
        int ea = e0 + gr;       if (ea >= E) ea = E - 1;
        int eb = e0 + gr + 32;  if (eb >= E) eb = E - 1;
        iA0 = ei0[ea]; iA1 = ei1[ea];
        iB0 = ei0[eb]; iB1 = ei1[eb];
    };
    auto issue_rows = [&]() {                     // row gathers (HBM/L3)
        const f4* pa = (const f4*)(x_src + (size_t)iA0 * HID + gc);
        const f4* qa = (const f4*)(x_dst + (size_t)iA1 * HID + gc);
        const f4* pb = (const f4*)(x_src + (size_t)iB0 * HID + gc);
        const f4* qb = (const f4*)(x_dst + (size_t)iB1 * HID + gc);
        PA0 = pa[0]; PA1 = pa[1]; QA0 = qa[0]; QA1 = qa[1];
        PB0 = pb[0]; PB1 = pb[1]; QB0 = qb[0]; QB1 = qb[1];
    };
    auto convert_store = [&]() {                  // consume prefetched rows
        #pragma unroll
        for (int i = 0; i < 2; ++i) {
            int r = gr + i * 32;
            f4 p0 = i ? PB0 : PA0, p1 = i ? PB1 : PA1;
            f4 q0 = i ? QB0 : QA0, q1 = i ? QB1 : QA1;
            v8s pbv, qbv, dbv;
            #pragma unroll
            for (int j = 0; j < 4; ++j) {
                pbv[j]     = (short)f2b(p0[j]);
                pbv[j + 4] = (short)f2b(p1[j]);
                qbv[j]     = (short)f2b(q0[j]);
                qbv[j + 4] = (short)f2b(q1[j]);
                dbv[j]     = (short)f2b(fabsf(p0[j] - q0[j]));
                dbv[j + 4] = (short)f2b(fabsf(p1[j] - q1[j]));
            }
            *(v8s*)&sEF[r * EFS       + gc] = pbv;
            *(v8s*)&sEF[r * EFS + 128 + gc] = qbv;
            *(v8s*)&sEF[r * EFS + 256 + gc] = dbv;
        }
    };

    int tile = blockIdx.x;
    if (tile < ntiles) { pre_issue(tile); issue_rows(); }

    for (; tile < ntiles; tile += PBLK) {
        int nxt = tile + PBLK;
        if (nxt < ntiles) pre_issue(nxt);   // ei loads fly during convert
        convert_store();                    // vmcnt-waits only the row loads
        barw();                             // publish EF
        if (nxt < ntiles) issue_rows();     // next gather flies across stages

        // ---------------- stage 1: enc_p / enc_c (K=128) ----------------
        v4f aP[2][2], aC[2][2];
        float bpv[2], bcv[2];
        #pragma unroll
        for (int nt = 0; nt < 2; ++nt) {
            bpv[nt] = bp[c0 + nt * 16 + ln];
            bcv[nt] = bc[c0 + nt * 16 + ln];
        }
        {   // P-GEMM
            v8s B[2][4];
            #pragma unroll
            for (int nt = 0; nt < 2; ++nt) {
                int n = c0 + nt * 16 + ln;
                #pragma unroll
                for (int kt = 0; kt < 4; ++kt)
                    B[nt][kt] = *(const v8s*)(wsWp + (size_t)n * HID + kt * 32 + lq * 8);
            }
            #pragma unroll
            for (int mt = 0; mt < 2; ++mt) {
                const int rb = (r0 + mt * 16 + ln) * EFS + lq * 8;
                v8s A[4];
                #pragma unroll
                for (int kt = 0; kt < 4; ++kt) A[kt] = *(const v8s*)&sEF[rb + kt * 32];
                #pragma unroll
                for (int nt = 0; nt < 2; ++nt) {
                    aP[mt][nt] = (v4f){0.f, 0.f, 0.f, 0.f};
                    #pragma unroll
                    for (int kt = 0; kt < 4; ++kt) aP[mt][nt] = MFMA(A[kt], B[nt][kt], aP[mt][nt]);
                }
            }
        }
        // C-GEMM: nt-outer (single B[4] live) for register headroom
        #pragma unroll
        for (int nt = 0; nt < 2; ++nt) {
            v8s B[4];
            int n = c0 + nt * 16 + ln;
            #pragma unroll
            for (int kt = 0; kt < 4; ++kt)
                B[kt] = *(const v8s*)(wsWc + (size_t)n * HID + kt * 32 + lq * 8);
            #pragma unroll
            for (int mt = 0; mt < 2; ++mt) {
                const int rb = (r0 + mt * 16 + ln) * EFS + 128 + lq * 8;
                v8s A[4];
                #pragma unroll
                for (int kt = 0; kt < 4; ++kt) A[kt] = *(const v8s*)&sEF[rb + kt * 32];
                aC[mt][nt] = (v4f){0.f, 0.f, 0.f, 0.f};
                #pragma unroll
                for (int kt = 0; kt < 4; ++kt) aC[mt][nt] = MFMA(A[kt], B[kt], aC[mt][nt]);
            }
        }
        barw();   // all waves done reading par/cld before overwrite
        #pragma unroll
        for (int mt = 0; mt < 2; ++mt)
            #pragma unroll
            for (int nt = 0; nt < 2; ++nt)
                #pragma unroll
                for (int rg = 0; rg < 4; ++rg) {
                    int row = r0 + mt * 16 + lq * 4 + rg;
                    int col = c0 + nt * 16 + ln;
                    float vp = aP[mt][nt][rg] + bpv[nt];
                    vp = vp > 0.f ? vp : 0.01f * vp;
                    sEF[row * EFS + col] = f2b(vp);
                    float vc = aC[mt][nt][rg] + bcv[nt];
                    vc = vc > 0.f ? vc : 0.01f * vc;
                    sEF[row * EFS + 128 + col] = f2b(vc);
                }
        barw();

        // ---------------- stage 2: H = relu(EF @ W1^T + b1)  (K=384) ----------------
        {
            float b1v[2];
            #pragma unroll
            for (int nt = 0; nt < 2; ++nt) b1v[nt] = b1[c0 + nt * 16 + ln];
            v4f acc[2][2];
            #pragma unroll
            for (int mt = 0; mt < 2; ++mt)
                #pragma unroll
                for (int nt = 0; nt < 2; ++nt) acc[mt][nt] = (v4f){0.f, 0.f, 0.f, 0.f};
            #pragma unroll
            for (int ktc = 0; ktc < 3; ++ktc) {          // K chunks of 128
                v8s B[2][4];
                #pragma unroll
                for (int nt = 0; nt < 2; ++nt) {
                    int n = c0 + nt * 16 + ln;
                    #pragma unroll
                    for (int k4 = 0; k4 < 4; ++k4)
                        B[nt][k4] = *(const v8s*)(wsW1 + (size_t)n * 384 + ktc * 128 + k4 * 32 + lq * 8);
                }
                #pragma unroll
                for (int mt = 0; mt < 2; ++mt) {
                    const int rb = (r0 + mt * 16 + ln) * EFS + ktc * 128 + lq * 8;
                    v8s A[4];
                    #pragma unroll
                    for (int k4 = 0; k4 < 4; ++k4) A[k4] = *(const v8s*)&sEF[rb + k4 * 32];
                    #pragma unroll
                    for (int nt = 0; nt < 2; ++nt)
                        #pragma unroll
                        for (int k4 = 0; k4 < 4; ++k4) acc[mt][nt] = MFMA(A[k4], B[nt][k4], acc[mt][nt]);
                }
            }
            barw();   // ALL waves done reading EF (incl. diff cols) before H overwrites
            #pragma unroll
            for (int mt = 0; mt < 2; ++mt)
                #pragma unroll
                for (int nt = 0; nt < 2; ++nt)
                    #pragma unroll
                    for (int rg = 0; rg < 4; ++rg) {
                        int row = r0 + mt * 16 + lq * 4 + rg;
                        int col = c0 + nt * 16 + ln;
                        float v = acc[mt][nt][rg] + b1v[nt];
                        sEF[row * EFS + 256 + col] = f2b(fmaxf(v, 0.f));   // H in dead diff region
                    }
            barw();
        }

        // ---------------- stage 3: out = H @ W2^T + b2  (K=128) ----------------
        {
            float b2v[2];
            #pragma unroll
            for (int nt = 0; nt < 2; ++nt) b2v[nt] = b2[c0 + nt * 16 + ln];
            v4f acc[2][2];
            v8s B[2][4];
            #pragma unroll
            for (int nt = 0; nt < 2; ++nt) {
                int n = c0 + nt * 16 + ln;
                #pragma unroll
                for (int kt = 0; kt < 4; ++kt)
                    B[nt][kt] = *(const v8s*)(wsW2 + (size_t)n * HID + kt * 32 + lq * 8);
            }
            #pragma unroll
            for (int mt = 0; mt < 2; ++mt) {
                const int rb = (r0 + mt * 16 + ln) * EFS + 256 + lq * 8;
                v8s A[4];
                #pragma unroll
                for (int kt = 0; kt < 4; ++kt) A[kt] = *(const v8s*)&sEF[rb + kt * 32];
                #pragma unroll
                for (int nt = 0; nt < 2; ++nt) {
                    acc[mt][nt] = (v4f){0.f, 0.f, 0.f, 0.f};
                    #pragma unroll
                    for (int kt = 0; kt < 4; ++kt) acc[mt][nt] = MFMA(A[kt], B[nt][kt], acc[mt][nt]);
                }
            }
            barw();   // all waves done reading H before fp32 staging overwrites sEF
            float* sF = (float*)sEF;     // 64 x FOS floats = 33792 B
            #pragma unroll
            for (int mt = 0; mt < 2; ++mt)
                #pragma unroll
                for (int nt = 0; nt < 2; ++nt)
                    #pragma unroll
                    for (int rg = 0; rg < 4; ++rg) {
                        int row = r0 + mt * 16 + lq * 4 + rg;
                        int col = c0 + nt * 16 + ln;
                        sF[row * FOS + col] = acc[mt][nt][rg] + b2v[nt];
                    }
            barw();
        }

        // ---------------- coalesced nontemporal fp32 store ----------------
        {
            const float* sF = (const float*)sEF;
            int e0s = tile * TM;
            #pragma unroll
            for (int i = 0; i < 4; ++i) {
                int idx2 = t + i * 512;     // 2048 float4 slots: 64 rows x 32 chunks
                int r = idx2 >> 5;
                int c = (idx2 & 31) << 2;
                int e = e0s + r;
                if (e < E) {
                    f4 vv = *(const f4*)&sF[r * FOS + c];
                    __builtin_nontemporal_store(vv, (f4*)(out + (size_t)e * HID + c));
                }
            }
        }
        barw();   // staging reads done before next-iter EF writes
    }
}

extern "C" void kernel_launch(void* const* d_in, const int* in_sizes, int n_in,
                              void* d_out, int out_size, void* d_ws, size_t ws_size,
                              hipStream_t stream) {
    const float* x_src = (const float*)d_in[0];
    const float* x_dst = (const float*)d_in[1];
    const int*   ei    = (const int*)d_in[2];
    const float* Wp    = (const float*)d_in[3];
    const float* bp    = (const float*)d_in[4];
    const float* Wc    = (const float*)d_in[5];
    const float* bc    = (const float*)d_in[6];
    const float* W1    = (const float*)d_in[7];
    const float* b1    = (const float*)d_in[8];
    const float* W2    = (const float*)d_in[9];
    const float* b2    = (const float*)d_in[10];
    float* out = (float*)d_out;
    u16* wsW = (u16*)d_ws;                    // 98304 u16 = 196608 B

    int E = in_sizes[2] / 2;                  // edge_index is [2, E]
    int ntiles = (E + TM - 1) / TM;

    cvt_weights<<<96, 256, 0, stream>>>(Wp, Wc, W1, W2, wsW);

    int blocks = ntiles < PBLK ? ntiles : PBLK;
    edge_attr_kernel<<<blocks, 512, 0, stream>>>(
        x_src, x_dst, ei, wsW, bp, bc, b1, b2, out, E, ntiles);
}

// Round 3
// 291.391 us; speedup vs baseline: 1.3404x; 1.3404x over previous
//
#include <hip/hip_runtime.h>

typedef unsigned short u16;
typedef __attribute__((ext_vector_type(8))) short v8s;   // 8 bf16 = 4 VGPRs
typedef __attribute__((ext_vector_type(4))) float v4f;   // MFMA accumulator / float4
typedef __attribute__((ext_vector_type(4))) float f4;

#define HID 128
#define TM  64          // edges per block
#define EFS 392         // EF LDS row stride (bf16 elements): 384 + 8 pad

__device__ __forceinline__ u16 f2b(float f) {            // fp32 -> bf16 RNE
    union { float f; unsigned u; } v; v.f = f;
    unsigned u = v.u;
    u += 0x7fffu + ((u >> 16) & 1u);
    return (u16)(u >> 16);
}

#define MFMA(A, B, C) __builtin_amdgcn_mfma_f32_16x16x32_bf16(A, B, C, 0, 0, 0)

// ---- weight fp32 -> bf16 pre-pass (once per launch, ~0.2 MB total) ----
// ws layout (u16 elems): Wp @0 (16384) | Wc @16384 | W1 @32768 (49152) | W2 @81920
__global__ void cvt_weights(const float* __restrict__ Wp, const float* __restrict__ Wc,
                            const float* __restrict__ W1, const float* __restrict__ W2,
                            u16* __restrict__ dst)
{
    int i = blockIdx.x * 256 + threadIdx.x;   // float4 index, 24576 total
    const float* s; int off;
    if (i < 4096)       { s = Wp; off = 0; }
    else if (i < 8192)  { s = Wc; off = 4096; }
    else if (i < 20480) { s = W1; off = 8192; }
    else                { s = W2; off = 20480; }
    int j = i - off;
    f4 v = ((const f4*)s)[j];
    u16* d = dst + (size_t)i * 4;
    d[0] = f2b(v[0]); d[1] = f2b(v[1]); d[2] = f2b(v[2]); d[3] = f2b(v[3]);
}

// Round-0 structure (256 thr, 4 waves each own a 64x32 output slice), with:
//  - sH eliminated (H lives in dead diff cols of sEF)  -> LDS 50176, 3 blocks/CU
//  - full-issue register gather (all 16 float4 loads in flight at once)
//  - stage-3 stores direct from accumulators (no LDS staging, 2 fewer barriers)
__global__ __launch_bounds__(256, 3) void edge_attr_kernel(
    const float* __restrict__ x_src, const float* __restrict__ x_dst,
    const int* __restrict__ ei,
    const u16* __restrict__ wsW,                 // converted weights in d_ws
    const float* __restrict__ bp, const float* __restrict__ bc,
    const float* __restrict__ b1, const float* __restrict__ b2,
    float* __restrict__ out, int E)
{
    __shared__ __align__(16) u16 sEF[TM * EFS];  // 50176 B

    const u16* wsWp = wsW;
    const u16* wsWc = wsW + 16384;
    const u16* wsW1 = wsW + 32768;
    const u16* wsW2 = wsW + 81920;

    const int t  = threadIdx.x;
    const int e0 = blockIdx.x * TM;
    const int* ei0 = ei;
    const int* ei1 = ei + E;

    // ---------------- gather: issue everything, then convert ----------------
    {
        const int gr = t >> 4;          // row base 0..15; thread covers gr+{0,16,32,48}
        const int gc = (t & 15) << 3;   // 8-float chunk

        int ia[4], ib[4];
        #pragma unroll
        for (int i = 0; i < 4; ++i) {
            int e = e0 + gr + i * 16; if (e >= E) e = E - 1;
            ia[i] = ei0[e]; ib[i] = ei1[e];
        }
        f4 P[4][2], Q[4][2];            // 16 float4 in flight (64 VGPR, gather-phase only)
        #pragma unroll
        for (int i = 0; i < 4; ++i) {
            const f4* ps = (const f4*)(x_src + (size_t)ia[i] * HID + gc);
            const f4* qs = (const f4*)(x_dst + (size_t)ib[i] * HID + gc);
            P[i][0] = ps[0]; P[i][1] = ps[1];
            Q[i][0] = qs[0]; Q[i][1] = qs[1];
        }
        #pragma unroll
        for (int i = 0; i < 4; ++i) {
            int r = gr + i * 16;
            f4 p0 = P[i][0], p1 = P[i][1], q0 = Q[i][0], q1 = Q[i][1];
            v8s pb, qb, db;
            #pragma unroll
            for (int j = 0; j < 4; ++j) {
                pb[j]     = (short)f2b(p0[j]);
                pb[j + 4] = (short)f2b(p1[j]);
                qb[j]     = (short)f2b(q0[j]);
                qb[j + 4] = (short)f2b(q1[j]);
                db[j]     = (short)f2b(fabsf(p0[j] - q0[j]));
                db[j + 4] = (short)f2b(fabsf(p1[j] - q1[j]));
            }
            *(v8s*)&sEF[r * EFS       + gc] = pb;
            *(v8s*)&sEF[r * EFS + 128 + gc] = qb;
            *(v8s*)&sEF[r * EFS + 256 + gc] = db;
        }
    }
    __syncthreads();

    const int lane = t & 63;
    const int ln = lane & 15;       // C-col / A-row within tile
    const int lq = lane >> 4;       // quad: k-base lq*8; C-row base lq*4
    const int n0 = (t >> 6) * 32;   // wave's output-column slice

    // ---------------- stage 1: enc_p / enc_c (K=128) ----------------
    {
        v8s Bp[2][4], Bc[2][4];
        float bpv[2], bcv[2];
        #pragma unroll
        for (int nt = 0; nt < 2; ++nt) {
            int n = n0 + nt * 16 + ln;
            bpv[nt] = bp[n];
            bcv[nt] = bc[n];
            #pragma unroll
            for (int kt = 0; kt < 4; ++kt) {
                Bp[nt][kt] = *(const v8s*)(wsWp + (size_t)n * HID + kt * 32 + lq * 8);
                Bc[nt][kt] = *(const v8s*)(wsWc + (size_t)n * HID + kt * 32 + lq * 8);
            }
        }
        v4f aP[4][2], aC[4][2];
        #pragma unroll
        for (int mt = 0; mt < 4; ++mt)
            #pragma unroll
            for (int nt = 0; nt < 2; ++nt) {
                aP[mt][nt] = (v4f){0.f, 0.f, 0.f, 0.f};
                aC[mt][nt] = (v4f){0.f, 0.f, 0.f, 0.f};
            }
        #pragma unroll
        for (int mt = 0; mt < 4; ++mt) {
            const int rbase = (mt * 16 + ln) * EFS + lq * 8;
            v8s A[4];
            #pragma unroll
            for (int kt = 0; kt < 4; ++kt) A[kt] = *(const v8s*)&sEF[rbase + kt * 32];
            #pragma unroll
            for (int nt = 0; nt < 2; ++nt)
                #pragma unroll
                for (int kt = 0; kt < 4; ++kt) aP[mt][nt] = MFMA(A[kt], Bp[nt][kt], aP[mt][nt]);
            #pragma unroll
            for (int kt = 0; kt < 4; ++kt) A[kt] = *(const v8s*)&sEF[rbase + 128 + kt * 32];
            #pragma unroll
            for (int nt = 0; nt < 2; ++nt)
                #pragma unroll
                for (int kt = 0; kt < 4; ++kt) aC[mt][nt] = MFMA(A[kt], Bc[nt][kt], aC[mt][nt]);
        }
        __syncthreads();   // all waves done reading par/cld before overwrite
        #pragma unroll
        for (int mt = 0; mt < 4; ++mt)
            #pragma unroll
            for (int nt = 0; nt < 2; ++nt)
                #pragma unroll
                for (int rg = 0; rg < 4; ++rg) {
                    int row = mt * 16 + lq * 4 + rg;
                    int col = n0 + nt * 16 + ln;
                    float vp = aP[mt][nt][rg] + bpv[nt];
                    vp = vp > 0.f ? vp : 0.01f * vp;
                    sEF[row * EFS + col] = f2b(vp);
                    float vc = aC[mt][nt][rg] + bcv[nt];
                    vc = vc > 0.f ? vc : 0.01f * vc;
                    sEF[row * EFS + 128 + col] = f2b(vc);
                }
        __syncthreads();
    }

    // ---------------- stage 2: H = relu(EF @ W1^T + b1)  (K=384) ----------------
    {
        float b1v[2];
        #pragma unroll
        for (int nt = 0; nt < 2; ++nt) b1v[nt] = b1[n0 + nt * 16 + ln];
        v4f acc[4][2];
        #pragma unroll
        for (int mt = 0; mt < 4; ++mt)
            #pragma unroll
            for (int nt = 0; nt < 2; ++nt) acc[mt][nt] = (v4f){0.f, 0.f, 0.f, 0.f};
        #pragma unroll
        for (int ktc = 0; ktc < 3; ++ktc) {          // K chunks of 128
            v8s B[2][4];
            #pragma unroll
            for (int nt = 0; nt < 2; ++nt) {
                int n = n0 + nt * 16 + ln;
                #pragma unroll
                for (int k4 = 0; k4 < 4; ++k4)
                    B[nt][k4] = *(const v8s*)(wsW1 + (size_t)n * 384 + ktc * 128 + k4 * 32 + lq * 8);
            }
            #pragma unroll
            for (int mt = 0; mt < 4; ++mt) {
                const int rbase = (mt * 16 + ln) * EFS + ktc * 128 + lq * 8;
                v8s A[4];
                #pragma unroll
                for (int k4 = 0; k4 < 4; ++k4) A[k4] = *(const v8s*)&sEF[rbase + k4 * 32];
                #pragma unroll
                for (int nt = 0; nt < 2; ++nt)
                    #pragma unroll
                    for (int k4 = 0; k4 < 4; ++k4) acc[mt][nt] = MFMA(A[k4], B[nt][k4], acc[mt][nt]);
            }
        }
        __syncthreads();   // ALL waves done reading EF (incl. diff cols) before H overwrites
        #pragma unroll
        for (int mt = 0; mt < 4; ++mt)
            #pragma unroll
            for (int nt = 0; nt < 2; ++nt)
                #pragma unroll
                for (int rg = 0; rg < 4; ++rg) {
                    int row = mt * 16 + lq * 4 + rg;
                    int col = n0 + nt * 16 + ln;
                    float v = acc[mt][nt][rg] + b1v[nt];
                    sEF[row * EFS + 256 + col] = f2b(fmaxf(v, 0.f));   // H in dead diff region
                }
        __syncthreads();
    }

    // ---------------- stage 3: out = H @ W2^T + b2, store direct ----------------
    {
        float b2v[2];
        v8s B2[2][4];
        #pragma unroll
        for (int nt = 0; nt < 2; ++nt) {
            int n = n0 + nt * 16 + ln;
            b2v[nt] = b2[n];
            #pragma unroll
            for (int kt = 0; kt < 4; ++kt)
                B2[nt][kt] = *(const v8s*)(wsW2 + (size_t)n * HID + kt * 32 + lq * 8);
        }
        #pragma unroll
        for (int mt = 0; mt < 4; ++mt) {
            const int rbase = (mt * 16 + ln) * EFS + 256 + lq * 8;
            v8s A[4];
            #pragma unroll
            for (int kt = 0; kt < 4; ++kt) A[kt] = *(const v8s*)&sEF[rbase + kt * 32];
            v4f acc[2];
            #pragma unroll
            for (int nt = 0; nt < 2; ++nt) {
                acc[nt] = (v4f){0.f, 0.f, 0.f, 0.f};
                #pragma unroll
                for (int kt = 0; kt < 4; ++kt) acc[nt] = MFMA(A[kt], B2[nt][kt], acc[nt]);
            }
            // direct coalesced store: 16 lanes cover 64 contiguous bytes per (row,nt)
            #pragma unroll
            for (int nt = 0; nt < 2; ++nt)
                #pragma unroll
                for (int rg = 0; rg < 4; ++rg) {
                    int row = mt * 16 + lq * 4 + rg;
                    int col = n0 + nt * 16 + ln;
                    int e = e0 + row;
                    if (e < E)
                        out[(size_t)e * HID + col] = acc[nt][rg] + b2v[nt];
                }
        }
    }
}

extern "C" void kernel_launch(void* const* d_in, const int* in_sizes, int n_in,
                              void* d_out, int out_size, void* d_ws, size_t ws_size,
                              hipStream_t stream) {
    const float* x_src = (const float*)d_in[0];
    const float* x_dst = (const float*)d_in[1];
    const int*   ei    = (const int*)d_in[2];
    const float* Wp    = (const float*)d_in[3];
    const float* bp    = (const float*)d_in[4];
    const float* Wc    = (const float*)d_in[5];
    const float* bc    = (const float*)d_in[6];
    const float* W1    = (const float*)d_in[7];
    const float* b1    = (const float*)d_in[8];
    const float* W2    = (const float*)d_in[9];
    const float* b2    = (const float*)d_in[10];
    float* out = (float*)d_out;
    u16* wsW = (u16*)d_ws;                    // 98304 u16 = 196608 B

    int E = in_sizes[2] / 2;                  // edge_index is [2, E]

    cvt_weights<<<96, 256, 0, stream>>>(Wp, Wc, W1, W2, wsW);

    int blocks = (E + TM - 1) / TM;
    edge_attr_kernel<<<blocks, 256, 0, stream>>>(
        x_src, x_dst, ei, wsW, bp, bc, b1, b2, out, E);
}